// Round 7
// baseline (617.175 us; speedup 1.0000x reference)
//
#include <hip/hip_runtime.h>
#include <hip/hip_bf16.h>

#define DIN 128
#define DHID 128
#define DCLS 64
#define BN_EPS 1e-5f
#define GEN_EPS 1e-7f

typedef __attribute__((ext_vector_type(8))) short short8;
typedef __attribute__((ext_vector_type(4))) float f32x4;

static __device__ __forceinline__ float bf2f(unsigned short u) {
    union { float f; unsigned int i; } x; x.i = ((unsigned int)u) << 16; return x.f;
}
static __device__ __forceinline__ unsigned short f2bf(float f) {
    union { float f; unsigned int i; } x; x.f = f;
    unsigned int r = x.i + 0x7fffu + ((x.i >> 16) & 1u);
    return (unsigned short)(r >> 16);
}
static __device__ __forceinline__ float bflo(unsigned int u) {
    union { float f; unsigned int i; } x; x.i = u << 16; return x.f;
}
static __device__ __forceinline__ float bfhi(unsigned int u) {
    union { float f; unsigned int i; } x; x.i = u & 0xffff0000u; return x.f;
}
static __device__ __forceinline__ unsigned int packbf(float lo, float hi) {
    return ((unsigned int)f2bf(hi) << 16) | f2bf(lo);
}

// ---------------- CSR build ----------------
__global__ void k_hist(const int* __restrict__ dst, int* __restrict__ counts, int E) {
    int e = blockIdx.x * 256 + threadIdx.x;
    if (e < E) atomicAdd(&counts[dst[e]], 1);
}

__global__ __launch_bounds__(256) void k_scan1(const int* __restrict__ counts,
        int* __restrict__ roff, int* __restrict__ bsum, int N) {
    __shared__ int ls[256];
    int t = threadIdx.x;
    int base = blockIdx.x * 1024 + t * 4;
    int c0 = 0, c1 = 0, c2 = 0, c3 = 0;
    if (base + 3 < N) {
        int4 v = *(const int4*)(counts + base);
        c0 = v.x; c1 = v.y; c2 = v.z; c3 = v.w;
    } else {
        if (base + 0 < N) c0 = counts[base + 0];
        if (base + 1 < N) c1 = counts[base + 1];
        if (base + 2 < N) c2 = counts[base + 2];
        if (base + 3 < N) c3 = counts[base + 3];
    }
    ls[t] = c0 + c1 + c2 + c3;
    __syncthreads();
    for (int off = 1; off < 256; off <<= 1) {
        int v = (t >= off) ? ls[t - off] : 0;
        __syncthreads();
        ls[t] += v;
        __syncthreads();
    }
    int r = (t == 0) ? 0 : ls[t - 1];
    if (base + 0 < N) { roff[base + 0] = r; r += c0; }
    if (base + 1 < N) { roff[base + 1] = r; r += c1; }
    if (base + 2 < N) { roff[base + 2] = r; r += c2; }
    if (base + 3 < N) { roff[base + 3] = r; }
    if (t == 255) bsum[blockIdx.x] = ls[255];
}

__global__ __launch_bounds__(1024) void k_scan2(int* __restrict__ bsum, int nblk) {
    __shared__ int ls[1024];
    int t = threadIdx.x;
    ls[t] = (t < nblk) ? bsum[t] : 0;
    __syncthreads();
    for (int off = 1; off < 1024; off <<= 1) {
        int v = (t >= off) ? ls[t - off] : 0;
        __syncthreads();
        ls[t] += v;
        __syncthreads();
    }
    if (t < nblk) bsum[t] = (t == 0) ? 0 : ls[t - 1];
}

__global__ void k_scan3(const int* __restrict__ counts, const int* __restrict__ bsum,
        int* __restrict__ roff, int* __restrict__ cursor, float* __restrict__ dinv,
        int N, int E) {
    int i = blockIdx.x * 256 + threadIdx.x;
    if (i < N) {
        int r = roff[i] + bsum[i >> 10];
        roff[i] = r; cursor[i] = r;
        dinv[i] = rsqrtf((float)(counts[i] + 1));
    }
    if (i == 0) roff[N] = E;
}

__global__ void k_fill(const int* __restrict__ src, const int* __restrict__ dst,
        int* __restrict__ cursor, int* __restrict__ srcs, int E) {
    int e = blockIdx.x * 256 + threadIdx.x;
    if (e < E) {
        int d = dst[e];
        int p = atomicAdd(&cursor[d], 1);
        srcs[p] = src[e];
    }
}

// ---------------- weight transpose to bf16: Wt[n][k] = W[k][n] ----------------
__global__ void k_wt(const float* __restrict__ W, unsigned short* __restrict__ Wt, int K, int Dout) {
    int i = blockIdx.x * 256 + threadIdx.x;
    if (i >= K * Dout) return;
    int n = i / K, k = i - n * K;
    Wt[i] = f2bf(W[(size_t)k * Dout + n]);
}

// ---------------- GEMM: C[nrows,Dout] = op(A)[nrows,K] @ W[K,Dout] (+bias, *rowscale) ----------------
// SLICED: bf16 output written channel-slice-major: C[cgl>>4][row][cgl&15] (slice stride nrows*16)
template<int K, bool ABF16, bool OBF16, bool SLICED>
__global__ __launch_bounds__(256) void k_gemm(const void* __restrict__ Av,
        const unsigned short* __restrict__ Wt, const float* __restrict__ bias,
        const float* __restrict__ scale, const float* __restrict__ shift,
        const float* __restrict__ rowscale,
        void* __restrict__ Cv, int nrows, int Dout) {
    constexpr int KP = K + 8;
    __shared__ unsigned short sA[64 * KP];
    __shared__ unsigned short sW[64 * KP];
    const int tid = threadIdx.x;
    const int row0 = blockIdx.x * 64, col0 = blockIdx.y * 64;

#pragma unroll
    for (int it = 0; it < (64 * K) / (256 * 4); ++it) {
        int idx = (it * 256 + tid) * 4;
        int r = idx / K, c = idx % K;
        int gr = row0 + r;
        float v0 = 0.f, v1 = 0.f, v2 = 0.f, v3 = 0.f;
        if (gr < nrows) {
            if (ABF16) {
                ushort4 u = *(const ushort4*)((const unsigned short*)Av + (size_t)gr * K + c);
                v0 = bf2f(u.x); v1 = bf2f(u.y); v2 = bf2f(u.z); v3 = bf2f(u.w);
            } else {
                float4 f = *(const float4*)((const float*)Av + (size_t)gr * K + c);
                v0 = f.x; v1 = f.y; v2 = f.z; v3 = f.w;
            }
            if (scale) {
                v0 = fmaxf(v0 * scale[c + 0] + shift[c + 0], 0.f);
                v1 = fmaxf(v1 * scale[c + 1] + shift[c + 1], 0.f);
                v2 = fmaxf(v2 * scale[c + 2] + shift[c + 2], 0.f);
                v3 = fmaxf(v3 * scale[c + 3] + shift[c + 3], 0.f);
            }
        }
        ushort4 o; o.x = f2bf(v0); o.y = f2bf(v1); o.z = f2bf(v2); o.w = f2bf(v3);
        *(ushort4*)(&sA[r * KP + c]) = o;
    }
#pragma unroll
    for (int it = 0; it < (64 * K) / (256 * 8); ++it) {
        int idx = (it * 256 + tid) * 8;
        int r = idx / K, c = idx % K;
        uint4 u = *(const uint4*)(Wt + (size_t)(col0 + r) * K + c);
        *(uint4*)(&sW[r * KP + c]) = u;
    }
    __syncthreads();

    const int w = tid >> 6, lane = tid & 63;
    const int wr = (w >> 1) * 32, wc = (w & 1) * 32;
    const int lr = lane & 15, kg = (lane >> 4) * 8;
    f32x4 acc[2][2] = {};
#pragma unroll
    for (int kk = 0; kk < K; kk += 32) {
        short8 af[2], bfr[2];
#pragma unroll
        for (int mi = 0; mi < 2; mi++)
            af[mi] = *(const short8*)(&sA[(wr + mi * 16 + lr) * KP + kk + kg]);
#pragma unroll
        for (int ni = 0; ni < 2; ni++)
            bfr[ni] = *(const short8*)(&sW[(wc + ni * 16 + lr) * KP + kk + kg]);
#pragma unroll
        for (int mi = 0; mi < 2; mi++)
#pragma unroll
            for (int ni = 0; ni < 2; ni++)
                acc[mi][ni] = __builtin_amdgcn_mfma_f32_16x16x32_bf16(af[mi], bfr[ni], acc[mi][ni], 0, 0, 0);
    }
#pragma unroll
    for (int mi = 0; mi < 2; mi++) {
#pragma unroll
        for (int ni = 0; ni < 2; ni++) {
            int r = wr + mi * 16 + (lane >> 4) * 4;
            int cgl = col0 + wc + ni * 16 + (lane & 15);
            float bv = bias ? bias[cgl] : 0.f;
#pragma unroll
            for (int j = 0; j < 4; j++) {
                int gr = row0 + r + j;
                if (gr < nrows) {
                    float val = acc[mi][ni][j] + bv;
                    if (rowscale) val *= rowscale[gr];
                    if (OBF16) {
                        size_t addr = SLICED
                            ? ((size_t)(cgl >> 4) * nrows + gr) * 16 + (cgl & 15)
                            : (size_t)gr * Dout + cgl;
                        ((unsigned short*)Cv)[addr] = f2bf(val);
                    } else {
                        ((float*)Cv)[(size_t)gr * Dout + cgl] = val;
                    }
                }
            }
        }
    }
}

// ---------------- GCN aggregation, channel-sliced (8 slices x 16 ch) ----------------
// p sliced [8][N][16] bf16 (premultiplied dinv.*h). slice = blockIdx.x & 7 (XCD-bound).
// wave per dst node: 16 edge-groups x 4 lanes, lane loads 8 B (4 ch).
// out row-major; fused BN stats for this slice's 16 channels.
__global__ __launch_bounds__(256) void k_gcn_agg(const unsigned short* __restrict__ p,
        const int* __restrict__ roff, const int* __restrict__ srcs,
        const float* __restrict__ dinv, const float* __restrict__ b,
        unsigned short* __restrict__ out,
        float* __restrict__ gsum, float* __restrict__ gsq, int N) {
    int slice = blockIdx.x & 7;
    int c0 = slice * 16;
    const unsigned short* ps = p + (size_t)slice * N * 16;
    int wv = threadIdx.x >> 6;
    int lane = threadIdx.x & 63;
    int grp = lane >> 2, l4 = lane & 3;
    int wid = (blockIdx.x >> 3) * 4 + wv;
    int nw = (gridDim.x >> 3) * 4;
    float4 bv4 = *(const float4*)(b + c0 + l4 * 4);
    float ls0 = 0.f, ls1 = 0.f, ls2 = 0.f, ls3 = 0.f;
    float lq0 = 0.f, lq1 = 0.f, lq2 = 0.f, lq3 = 0.f;
    for (int d = wid; d < N; d += nw) {
        float a0 = 0.f, a1 = 0.f, a2 = 0.f, a3 = 0.f;
        int e0 = roff[d], e1 = roff[d + 1];
        for (int e = e0 + grp; e < e1; e += 16) {
            int s = srcs[e];
            uint2 u = *(const uint2*)(ps + (size_t)s * 16 + l4 * 4);
            a0 += bflo(u.x); a1 += bfhi(u.x);
            a2 += bflo(u.y); a3 += bfhi(u.y);
        }
        if (grp == 0) { // self term once
            uint2 u = *(const uint2*)(ps + (size_t)d * 16 + l4 * 4);
            a0 += bflo(u.x); a1 += bfhi(u.x);
            a2 += bflo(u.y); a3 += bfhi(u.y);
        }
        for (int off = 4; off < 64; off <<= 1) {
            a0 += __shfl_xor(a0, off); a1 += __shfl_xor(a1, off);
            a2 += __shfl_xor(a2, off); a3 += __shfl_xor(a3, off);
        }
        if (grp == 0) {
            float dv = dinv[d];
            float r0 = dv * a0 + bv4.x, r1 = dv * a1 + bv4.y;
            float r2 = dv * a2 + bv4.z, r3 = dv * a3 + bv4.w;
            ls0 += r0; lq0 += r0 * r0; ls1 += r1; lq1 += r1 * r1;
            ls2 += r2; lq2 += r2 * r2; ls3 += r3; lq3 += r3 * r3;
            uint2 o; o.x = packbf(r0, r1); o.y = packbf(r2, r3);
            *(uint2*)(out + (size_t)d * 128 + c0 + l4 * 4) = o;
        }
    }
    __shared__ float sred[4][16];
    __shared__ float qred[4][16];
    if (grp == 0) {
        sred[wv][l4 * 4 + 0] = ls0; sred[wv][l4 * 4 + 1] = ls1;
        sred[wv][l4 * 4 + 2] = ls2; sred[wv][l4 * 4 + 3] = ls3;
        qred[wv][l4 * 4 + 0] = lq0; qred[wv][l4 * 4 + 1] = lq1;
        qred[wv][l4 * 4 + 2] = lq2; qred[wv][l4 * 4 + 3] = lq3;
    }
    __syncthreads();
    int t = threadIdx.x;
    if (t < 16) {
        float s = sred[0][t] + sred[1][t] + sred[2][t] + sred[3][t];
        float qq = qred[0][t] + qred[1][t] + qred[2][t] + qred[3][t];
        atomicAdd(&gsum[c0 + t], s);
        atomicAdd(&gsq[c0 + t], qq);
    }
}

// ---------------- GEN precompute into sliced table [8][N][w16|wm16] ----------------
__global__ __launch_bounds__(256) void k_genpre(const unsigned short* __restrict__ t4,
        const float* __restrict__ scale, const float* __restrict__ shift,
        unsigned short* __restrict__ wt, int N) {
    int i = blockIdx.x * 256 + threadIdx.x;
    int node = i >> 4, l16 = i & 15;
    if (node >= N) return;
    int c = l16 * 8;
    float4 scl = *(const float4*)(scale + c);
    float4 sch = *(const float4*)(scale + c + 4);
    float4 shl = *(const float4*)(shift + c);
    float4 shh = *(const float4*)(shift + c + 4);
    float sc[8] = {scl.x, scl.y, scl.z, scl.w, sch.x, sch.y, sch.z, sch.w};
    float sh[8] = {shl.x, shl.y, shl.z, shl.w, shh.x, shh.y, shh.z, shh.w};
    uint4 u = ((const uint4*)(t4 + (size_t)node * 128))[l16];
    float v[8] = {bflo(u.x), bfhi(u.x), bflo(u.y), bfhi(u.y),
                  bflo(u.z), bfhi(u.z), bflo(u.w), bfhi(u.w)};
    float w[8], wm[8];
#pragma unroll
    for (int k = 0; k < 8; k++) {
        float m = fmaxf(v[k] * sc[k] + sh[k], 0.f) + GEN_EPS;
        m = fminf(m, 80.f);
        w[k] = __expf(m);
        wm[k] = w[k] * m;
    }
    int slice = l16 >> 1, half = l16 & 1;
    unsigned short* base = wt + (size_t)slice * N * 32 + (size_t)node * 32 + half * 8;
    uint4 ow, om;
    ow.x = packbf(w[0], w[1]); ow.y = packbf(w[2], w[3]);
    ow.z = packbf(w[4], w[5]); ow.w = packbf(w[6], w[7]);
    om.x = packbf(wm[0], wm[1]); om.y = packbf(wm[2], wm[3]);
    om.z = packbf(wm[4], wm[5]); om.w = packbf(wm[6], wm[7]);
    *(uint4*)base = ow;
    *(uint4*)(base + 16) = om;
}

// ---------------- GEN softmax aggregation, channel-sliced ----------------
// wt sliced [8][N][32]: per node 16 w then 16 wm. 8 edge-groups x 8 lanes; lane loads 8 B.
// lanes l8<4 accumulate de (w), l8>=4 accumulate nu (wm).
__global__ __launch_bounds__(256) void k_gen_agg(const unsigned short* __restrict__ t4,
        const unsigned short* __restrict__ wt,
        const int* __restrict__ roff, const int* __restrict__ srcs,
        const float* __restrict__ scale, const float* __restrict__ shift,
        unsigned short* __restrict__ out, int N) {
    int slice = blockIdx.x & 7;
    int c0 = slice * 16;
    const unsigned short* wts = wt + (size_t)slice * N * 32;
    int wv = threadIdx.x >> 6;
    int lane = threadIdx.x & 63;
    int grp = lane >> 3, l8 = lane & 7;
    int wid = (blockIdx.x >> 3) * 4 + wv;
    int nw = (gridDim.x >> 3) * 4;
    for (int d = wid; d < N; d += nw) {
        float a0 = 0.f, a1 = 0.f, a2 = 0.f, a3 = 0.f;
        int e0 = roff[d], e1 = roff[d + 1];
        for (int e = e0 + grp; e < e1; e += 8) {
            int s = srcs[e];
            uint2 u = *(const uint2*)(wts + (size_t)s * 32 + l8 * 4);
            a0 += bflo(u.x); a1 += bfhi(u.x);
            a2 += bflo(u.y); a3 += bfhi(u.y);
        }
        for (int off = 8; off < 64; off <<= 1) {
            a0 += __shfl_xor(a0, off); a1 += __shfl_xor(a1, off);
            a2 += __shfl_xor(a2, off); a3 += __shfl_xor(a3, off);
        }
        // lanes 0-7 hold sums: l8<4 -> de, l8>=4 -> nu. bring nu to lanes 0-3.
        float n0 = __shfl_xor(a0, 4), n1 = __shfl_xor(a1, 4);
        float n2 = __shfl_xor(a2, 4), n3 = __shfl_xor(a3, 4);
        if (grp == 0 && l8 < 4) {
            bool has = (e1 > e0);
            float i0 = has ? n0 / a0 : 0.f;
            float i1 = has ? n1 / a1 : 0.f;
            float i2 = has ? n2 / a2 : 0.f;
            float i3 = has ? n3 / a3 : 0.f;
            int cc = c0 + l8 * 4;
            float4 sc4 = *(const float4*)(scale + cc);
            float4 sh4 = *(const float4*)(shift + cc);
            uint2 u = *(const uint2*)(t4 + (size_t)d * 128 + cc);
            float r0 = i0 + fmaxf(bflo(u.x) * sc4.x + sh4.x, 0.f);
            float r1 = i1 + fmaxf(bfhi(u.x) * sc4.y + sh4.y, 0.f);
            float r2 = i2 + fmaxf(bflo(u.y) * sc4.z + sh4.z, 0.f);
            float r3 = i3 + fmaxf(bfhi(u.y) * sc4.w + sh4.w, 0.f);
            uint2 o; o.x = packbf(r0, r1); o.y = packbf(r2, r3);
            *(uint2*)(out + (size_t)d * 128 + cc) = o;
        }
    }
}

// ---------------- BN column stats (for MLP hidden, D=256) ----------------
template<int D>
__global__ __launch_bounds__(256) void k_stats(const unsigned short* __restrict__ h,
        float* __restrict__ gsum, float* __restrict__ gsq, int N) {
    constexpr int HC = D / 2, TPC = 256 / HC;
    int t = threadIdx.x;
    int cp = t % HC, slot = t / HC;
    int c = cp * 2;
    float s0 = 0.f, s1 = 0.f, q0 = 0.f, q1 = 0.f;
    for (int node = blockIdx.x * TPC + slot; node < N; node += gridDim.x * TPC) {
        ushort2 u = *(const ushort2*)(h + (size_t)node * D + c);
        float v0 = bf2f(u.x), v1 = bf2f(u.y);
        s0 += v0; s1 += v1; q0 += v0 * v0; q1 += v1 * v1;
    }
    __shared__ float red[256 * 4];
    red[t * 4] = s0; red[t * 4 + 1] = s1; red[t * 4 + 2] = q0; red[t * 4 + 3] = q1;
    __syncthreads();
    if (slot == 0) {
        for (int k2 = 1; k2 < TPC; k2++) {
            int o = (t + k2 * HC) * 4;
            s0 += red[o]; s1 += red[o + 1]; q0 += red[o + 2]; q1 += red[o + 3];
        }
        atomicAdd(&gsum[c], s0); atomicAdd(&gsum[c + 1], s1);
        atomicAdd(&gsq[c], q0); atomicAdd(&gsq[c + 1], q1);
    }
}

__global__ void k_fin(const float* __restrict__ sum, const float* __restrict__ sq,
        const float* __restrict__ g, const float* __restrict__ beta,
        float* __restrict__ scale, float* __restrict__ shift, int D, float invN) {
    int c = threadIdx.x;
    if (c < D) {
        float mu = sum[c] * invN;
        float var = sq[c] * invN - mu * mu;
        float s = g[c] * rsqrtf(var + BN_EPS);
        scale[c] = s;
        shift[c] = beta[c] - mu * s;
    }
}

// ---------------- log_softmax in place, wave per row of 64 ----------------
__global__ __launch_bounds__(256) void k_head(float* __restrict__ out, int N) {
    int wid = blockIdx.x * 4 + (threadIdx.x >> 6);
    int lane = threadIdx.x & 63;
    if (wid >= N) return;
    float v = out[(size_t)wid * 64 + lane];
    float m = v;
    for (int o = 32; o; o >>= 1) m = fmaxf(m, __shfl_xor(m, o));
    float e = __expf(v - m);
    float s = e;
    for (int o = 32; o; o >>= 1) s += __shfl_xor(s, o);
    out[(size_t)wid * 64 + lane] = v - m - __logf(s);
}

extern "C" void kernel_launch(void* const* d_in, const int* in_sizes, int n_in,
                              void* d_out, int out_size, void* d_ws, size_t ws_size,
                              hipStream_t stream) {
    const float* x   = (const float*)d_in[0];
    const float* W0  = (const float*)d_in[1];
    const float* b0  = (const float*)d_in[2];
    const float* g0  = (const float*)d_in[3];
    const float* be0 = (const float*)d_in[4];
    const float* W1  = (const float*)d_in[5];
    const float* b1  = (const float*)d_in[6];
    const float* g1  = (const float*)d_in[7];
    const float* be1 = (const float*)d_in[8];
    const float* Wg1 = (const float*)d_in[9];
    const float* bg1 = (const float*)d_in[10];
    const float* gg  = (const float*)d_in[11];
    const float* beg = (const float*)d_in[12];
    const float* Wg2 = (const float*)d_in[13];
    const float* bg2 = (const float*)d_in[14];
    const int*   ei  = (const int*)d_in[15];

    const int N = in_sizes[0] / DIN;
    const int E = in_sizes[15] / 2;
    const int* src = ei;
    const int* dst = ei + E;

    char* ws = (char*)d_ws;
    size_t off = 0;
    auto alloc = [&](size_t b) { size_t o = off; off = (off + b + 255) & ~(size_t)255; return o; };
    size_t o_counts = alloc((size_t)N * 4);
    size_t o_stats  = alloc(1024 * 4);
    size_t o_cursor = alloc((size_t)N * 4);
    size_t o_roff   = alloc(((size_t)N + 1) * 4);
    size_t o_srcs   = alloc((size_t)E * 4);
    size_t o_dinv   = alloc((size_t)N * 4);
    size_t o_bsum   = alloc(1024 * 4);
    size_t o_ss     = alloc(1024 * 4);
    size_t o_w0t    = alloc(128 * 128 * 2);
    size_t o_w1t    = alloc(128 * 128 * 2);
    size_t o_wg1t   = alloc(256 * 128 * 2);
    size_t o_wg2t   = alloc(64 * 256 * 2);
    size_t o_xa     = alloc((size_t)N * 128 * 2);
    size_t o_xb     = alloc((size_t)N * 128 * 2);
    size_t o_c      = alloc((size_t)N * 256 * 2);   // MLP hidden; aliased as GEN sliced exp table
    (void)ws_size; (void)n_in; (void)out_size;

    int* counts = (int*)(ws + o_counts);
    float* stats = (float*)(ws + o_stats);
    int* cursor = (int*)(ws + o_cursor);
    int* roff = (int*)(ws + o_roff);
    int* srcs = (int*)(ws + o_srcs);
    float* dinv = (float*)(ws + o_dinv);
    int* bsum = (int*)(ws + o_bsum);
    float* ssz = (float*)(ws + o_ss);
    unsigned short* w0t  = (unsigned short*)(ws + o_w0t);
    unsigned short* w1t  = (unsigned short*)(ws + o_w1t);
    unsigned short* wg1t = (unsigned short*)(ws + o_wg1t);
    unsigned short* wg2t = (unsigned short*)(ws + o_wg2t);
    unsigned short* xa = (unsigned short*)(ws + o_xa);
    unsigned short* xb = (unsigned short*)(ws + o_xb);
    unsigned short* cb = (unsigned short*)(ws + o_c);
    unsigned short* wtab = cb;  // alias: sliced exp table lives in cb until MLP GEMM overwrites it

    float* sum0 = stats;       float* sq0 = stats + 128;
    float* sum1 = stats + 256; float* sq1 = stats + 384;
    float* sumg = stats + 512; float* sqg = stats + 768;
    float* scale0 = ssz;       float* shift0 = ssz + 128;
    float* scale1 = ssz + 256; float* shift1 = ssz + 384;
    float* scaleg = ssz + 512; float* shiftg = ssz + 768;

    hipMemsetAsync(ws + o_counts, 0, o_cursor - o_counts, stream);

    // CSR build (hierarchical scan)
    int egrid = (E + 255) / 256;
    int nblk = (N + 1023) / 1024;
    k_hist<<<egrid, 256, 0, stream>>>(dst, counts, E);
    k_scan1<<<nblk, 256, 0, stream>>>(counts, roff, bsum, N);
    k_scan2<<<1, 1024, 0, stream>>>(bsum, nblk);
    k_scan3<<<(N + 255) / 256, 256, 0, stream>>>(counts, bsum, roff, cursor, dinv, N, E);
    k_fill<<<egrid, 256, 0, stream>>>(src, dst, cursor, srcs, E);

    // weight transposes (bf16)
    k_wt<<<(128 * 128 + 255) / 256, 256, 0, stream>>>(W0, w0t, 128, 128);
    k_wt<<<(128 * 128 + 255) / 256, 256, 0, stream>>>(W1, w1t, 128, 128);
    k_wt<<<(128 * 256 + 255) / 256, 256, 0, stream>>>(Wg1, wg1t, 128, 256);
    k_wt<<<(256 * 64 + 255) / 256, 256, 0, stream>>>(Wg2, wg2t, 256, 64);

    int rb = (N + 63) / 64;
    const float invN = 1.f / (float)N;

    // layer 0: p0 = dinv.*(x@W0) -> xa SLICED ; sliced agg (+fused stats) -> xb row-major ; finalize BN
    k_gemm<128, false, true, true><<<dim3(rb, 2), 256, 0, stream>>>(x, w0t, nullptr, nullptr, nullptr, dinv, xa, N, 128);
    k_gcn_agg<<<2048, 256, 0, stream>>>(xa, roff, srcs, dinv, b0, xb, sum0, sq0, N);
    k_fin<<<1, 256, 0, stream>>>(sum0, sq0, g0, be0, scale0, shift0, 128, invN);

    // layer 1
    k_gemm<128, true, true, true><<<dim3(rb, 2), 256, 0, stream>>>(xb, w1t, nullptr, scale0, shift0, dinv, xa, N, 128);
    k_gcn_agg<<<2048, 256, 0, stream>>>(xa, roff, srcs, dinv, b1, xb, sum1, sq1, N);
    k_fin<<<1, 256, 0, stream>>>(sum1, sq1, g1, be1, scale1, shift1, 128, invN);

    // GEN conv: sliced exp tables, then sliced gather-sum -> xa row-major
    k_genpre<<<(N * 16 + 255) / 256, 256, 0, stream>>>(xb, scale1, shift1, wtab, N);
    k_gen_agg<<<2048, 256, 0, stream>>>(xb, wtab, roff, srcs, scale1, shift1, xa, N);

    // MLP: t7 = t6@Wg1+bg1 -> cb (overwrites exp table); stats; finalize; final GEMM -> d_out
    k_gemm<128, true, true, false><<<dim3(rb, 4), 256, 0, stream>>>(xa, wg1t, bg1, nullptr, nullptr, nullptr, cb, N, 256);
    k_stats<256><<<1024, 256, 0, stream>>>(cb, sumg, sqg, N);
    k_fin<<<1, 256, 0, stream>>>(sumg, sqg, gg, beg, scaleg, shiftg, 256, invN);
    k_gemm<256, true, false, false><<<dim3(rb, 1), 256, 0, stream>>>(cb, wg2t, bg2, scaleg, shiftg, nullptr, d_out, N, 64);

    // log_softmax in place
    k_head<<<(N + 3) / 4, 256, 0, stream>>>((float*)d_out, N);
}

// Round 8
// 477.711 us; speedup vs baseline: 1.2919x; 1.2919x over previous
//
#include <hip/hip_runtime.h>
#include <hip/hip_bf16.h>

#define DIN 128
#define DHID 128
#define DCLS 64
#define BN_EPS 1e-5f
#define GEN_EPS 1e-7f

typedef __attribute__((ext_vector_type(8))) short short8;
typedef __attribute__((ext_vector_type(4))) float f32x4;

static __device__ __forceinline__ float bf2f(unsigned short u) {
    union { float f; unsigned int i; } x; x.i = ((unsigned int)u) << 16; return x.f;
}
static __device__ __forceinline__ unsigned short f2bf(float f) {
    union { float f; unsigned int i; } x; x.f = f;
    unsigned int r = x.i + 0x7fffu + ((x.i >> 16) & 1u);
    return (unsigned short)(r >> 16);
}
static __device__ __forceinline__ float bflo(unsigned int u) {
    union { float f; unsigned int i; } x; x.i = u << 16; return x.f;
}
static __device__ __forceinline__ float bfhi(unsigned int u) {
    union { float f; unsigned int i; } x; x.i = u & 0xffff0000u; return x.f;
}
static __device__ __forceinline__ unsigned int packbf(float lo, float hi) {
    return ((unsigned int)f2bf(hi) << 16) | f2bf(lo);
}

// ---------------- CSR build ----------------
__global__ void k_hist(const int* __restrict__ dst, int* __restrict__ counts, int E) {
    int e = blockIdx.x * 256 + threadIdx.x;
    if (e < E) atomicAdd(&counts[dst[e]], 1);
}

__global__ __launch_bounds__(256) void k_scan1(const int* __restrict__ counts,
        int* __restrict__ roff, int* __restrict__ bsum, int N) {
    __shared__ int ls[256];
    int t = threadIdx.x;
    int base = blockIdx.x * 1024 + t * 4;
    int c0 = 0, c1 = 0, c2 = 0, c3 = 0;
    if (base + 3 < N) {
        int4 v = *(const int4*)(counts + base);
        c0 = v.x; c1 = v.y; c2 = v.z; c3 = v.w;
    } else {
        if (base + 0 < N) c0 = counts[base + 0];
        if (base + 1 < N) c1 = counts[base + 1];
        if (base + 2 < N) c2 = counts[base + 2];
        if (base + 3 < N) c3 = counts[base + 3];
    }
    ls[t] = c0 + c1 + c2 + c3;
    __syncthreads();
    for (int off = 1; off < 256; off <<= 1) {
        int v = (t >= off) ? ls[t - off] : 0;
        __syncthreads();
        ls[t] += v;
        __syncthreads();
    }
    int r = (t == 0) ? 0 : ls[t - 1];
    if (base + 0 < N) { roff[base + 0] = r; r += c0; }
    if (base + 1 < N) { roff[base + 1] = r; r += c1; }
    if (base + 2 < N) { roff[base + 2] = r; r += c2; }
    if (base + 3 < N) { roff[base + 3] = r; }
    if (t == 255) bsum[blockIdx.x] = ls[255];
}

__global__ __launch_bounds__(1024) void k_scan2(int* __restrict__ bsum, int nblk) {
    __shared__ int ls[1024];
    int t = threadIdx.x;
    ls[t] = (t < nblk) ? bsum[t] : 0;
    __syncthreads();
    for (int off = 1; off < 1024; off <<= 1) {
        int v = (t >= off) ? ls[t - off] : 0;
        __syncthreads();
        ls[t] += v;
        __syncthreads();
    }
    if (t < nblk) bsum[t] = (t == 0) ? 0 : ls[t - 1];
}

__global__ void k_scan3(const int* __restrict__ counts, const int* __restrict__ bsum,
        int* __restrict__ roff, int* __restrict__ cursor, float* __restrict__ dinv,
        int N, int E) {
    int i = blockIdx.x * 256 + threadIdx.x;
    if (i < N) {
        int r = roff[i] + bsum[i >> 10];
        roff[i] = r; cursor[i] = r;
        dinv[i] = rsqrtf((float)(counts[i] + 1));
    }
    if (i == 0) roff[N] = E;
}

__global__ void k_fill(const int* __restrict__ src, const int* __restrict__ dst,
        int* __restrict__ cursor, int* __restrict__ srcs, int E) {
    int e = blockIdx.x * 256 + threadIdx.x;
    if (e < E) {
        int d = dst[e];
        int p = atomicAdd(&cursor[d], 1);
        srcs[p] = src[e];
    }
}

// ---------------- weight transpose to bf16: Wt[n][k] = W[k][n] ----------------
__global__ void k_wt(const float* __restrict__ W, unsigned short* __restrict__ Wt, int K, int Dout) {
    int i = blockIdx.x * 256 + threadIdx.x;
    if (i >= K * Dout) return;
    int n = i / K, k = i - n * K;
    Wt[i] = f2bf(W[(size_t)k * Dout + n]);
}

// ---------------- GEMM: C[nrows,Dout] = op(A)[nrows,K] @ W[K,Dout] (+bias, *rowscale) ----------------
// 64-row x CTILE-col output tile; K staged in 128-chunks (LDS [64][136] + [CTILE][136]).
// STATS: fuse per-column sum/sumsq (BN stats) via LDS + global atomics.
// HEAD: fuse row log_softmax (requires CTILE == Dout == 64, f32 out).
template<int K, int CTILE, bool ABF16, bool OBF16, bool STATS, bool HEAD>
__global__ __launch_bounds__(256) void k_gemm(const void* __restrict__ Av,
        const unsigned short* __restrict__ Wt, const float* __restrict__ bias,
        const float* __restrict__ scale, const float* __restrict__ shift,
        const float* __restrict__ rowscale,
        void* __restrict__ Cv, float* __restrict__ gsum, float* __restrict__ gsq,
        int nrows, int Dout) {
    constexpr int KP = 136;            // 128-chunk + 8 pad
    constexpr int NF = CTILE / 32;     // col fragments per wave
    __shared__ unsigned short smem[(64 + CTILE) * KP];
    unsigned short* sA = smem;
    unsigned short* sW = smem + 64 * KP;
    const int tid = threadIdx.x;
    const int row0 = blockIdx.x * 64, col0 = blockIdx.y * CTILE;

    const int w = tid >> 6, lane = tid & 63;
    const int wr = (w >> 1) * 32, wc = (w & 1) * (CTILE / 2);
    const int lr = lane & 15, kg = (lane >> 4) * 8;
    f32x4 acc[2][NF] = {};

    for (int kh = 0; kh < K; kh += 128) {
        // stage A chunk: 64 rows x 128
#pragma unroll
        for (int it = 0; it < 8; ++it) {
            int idx = (it * 256 + tid) * 4;
            int r = idx >> 7, c = idx & 127;
            int gr = row0 + r;
            float v0 = 0.f, v1 = 0.f, v2 = 0.f, v3 = 0.f;
            if (gr < nrows) {
                if (ABF16) {
                    ushort4 u = *(const ushort4*)((const unsigned short*)Av + (size_t)gr * K + kh + c);
                    v0 = bf2f(u.x); v1 = bf2f(u.y); v2 = bf2f(u.z); v3 = bf2f(u.w);
                } else {
                    float4 f = *(const float4*)((const float*)Av + (size_t)gr * K + kh + c);
                    v0 = f.x; v1 = f.y; v2 = f.z; v3 = f.w;
                }
                if (scale) {
                    int cc = kh + c;
                    v0 = fmaxf(v0 * scale[cc + 0] + shift[cc + 0], 0.f);
                    v1 = fmaxf(v1 * scale[cc + 1] + shift[cc + 1], 0.f);
                    v2 = fmaxf(v2 * scale[cc + 2] + shift[cc + 2], 0.f);
                    v3 = fmaxf(v3 * scale[cc + 3] + shift[cc + 3], 0.f);
                }
            }
            ushort4 o; o.x = f2bf(v0); o.y = f2bf(v1); o.z = f2bf(v2); o.w = f2bf(v3);
            *(ushort4*)(&sA[r * KP + c]) = o;
        }
        // stage W chunk: CTILE rows x 128
#pragma unroll
        for (int it = 0; it < (CTILE * 128) / (256 * 8); ++it) {
            int idx = (it * 256 + tid) * 8;
            int r = idx >> 7, c = idx & 127;
            uint4 u = *(const uint4*)(Wt + (size_t)(col0 + r) * K + kh + c);
            *(uint4*)(&sW[r * KP + c]) = u;
        }
        __syncthreads();
#pragma unroll
        for (int kk = 0; kk < 128; kk += 32) {
            short8 af[2], bfr[NF];
#pragma unroll
            for (int mi = 0; mi < 2; mi++)
                af[mi] = *(const short8*)(&sA[(wr + mi * 16 + lr) * KP + kk + kg]);
#pragma unroll
            for (int ni = 0; ni < NF; ni++)
                bfr[ni] = *(const short8*)(&sW[(wc + ni * 16 + lr) * KP + kk + kg]);
#pragma unroll
            for (int mi = 0; mi < 2; mi++)
#pragma unroll
                for (int ni = 0; ni < NF; ni++)
                    acc[mi][ni] = __builtin_amdgcn_mfma_f32_16x16x32_bf16(af[mi], bfr[ni], acc[mi][ni], 0, 0, 0);
        }
        __syncthreads();
    }

    float* fs = (float*)smem;          // reused: stats accum or head tile
    if (STATS) {
        if (tid < 2 * CTILE) fs[tid] = 0.f;
        __syncthreads();
    }

    float stat_s[NF], stat_q[NF];
#pragma unroll
    for (int ni = 0; ni < NF; ni++) { stat_s[ni] = 0.f; stat_q[ni] = 0.f; }

#pragma unroll
    for (int mi = 0; mi < 2; mi++) {
#pragma unroll
        for (int ni = 0; ni < NF; ni++) {
            int r = wr + mi * 16 + (lane >> 4) * 4;
            int cloc = wc + ni * 16 + (lane & 15);
            int cgl = col0 + cloc;
            float bv = bias ? bias[cgl] : 0.f;
#pragma unroll
            for (int j = 0; j < 4; j++) {
                int gr = row0 + r + j;
                if (gr < nrows) {
                    float val = acc[mi][ni][j] + bv;
                    if (rowscale) val *= rowscale[gr];
                    if (STATS) { stat_s[ni] += val; stat_q[ni] += val * val; }
                    if (HEAD) {
                        fs[(r + j) * 65 + cloc] = val;
                    } else if (OBF16) {
                        ((unsigned short*)Cv)[(size_t)gr * Dout + cgl] = f2bf(val);
                    } else {
                        ((float*)Cv)[(size_t)gr * Dout + cgl] = val;
                    }
                } else if (HEAD) {
                    fs[(r + j) * 65 + cloc] = 0.f;
                }
            }
        }
    }

    if (STATS) {
#pragma unroll
        for (int ni = 0; ni < NF; ni++) {
            int cloc = wc + ni * 16 + (lane & 15);
            atomicAdd(&fs[cloc], stat_s[ni]);
            atomicAdd(&fs[CTILE + cloc], stat_q[ni]);
        }
        __syncthreads();
        if (tid < CTILE) {
            atomicAdd(&gsum[col0 + tid], fs[tid]);
            atomicAdd(&gsq[col0 + tid], fs[CTILE + tid]);
        }
    }

    if (HEAD) {
        __syncthreads();
        // wave w handles rows w*16 .. w*16+15; 64 lanes = 64 classes
        for (int rr = 0; rr < 16; rr++) {
            int row = w * 16 + rr;
            int gr = row0 + row;
            if (gr >= nrows) break;
            float v = fs[row * 65 + lane];
            float m = v;
            for (int o = 32; o; o >>= 1) m = fmaxf(m, __shfl_xor(m, o));
            float e = __expf(v - m);
            float s = e;
            for (int o = 32; o; o >>= 1) s += __shfl_xor(s, o);
            ((float*)Cv)[(size_t)gr * 64 + lane] = v - m - __logf(s);
        }
    }
}

#define ACC8(u) { a0 += bflo(u.x); a1 += bfhi(u.x); a2 += bflo(u.y); a3 += bfhi(u.y); \
                  a4 += bflo(u.z); a5 += bfhi(u.z); a6 += bflo(u.w); a7 += bfhi(u.w); }

// ---------------- GCN aggregation over premultiplied p = dinv.*h, fused BN stats ----------------
// wave per dst node; 4 edge-groups of 16 lanes; lane handles 8 channels (uint4).
__global__ __launch_bounds__(256) void k_gcn_agg(const unsigned short* __restrict__ p,
        const int* __restrict__ roff, const int* __restrict__ srcs,
        const float* __restrict__ dinv, const float* __restrict__ b,
        unsigned short* __restrict__ out,
        float* __restrict__ gsum, float* __restrict__ gsq, int N) {
    int nw = (gridDim.x * 256) >> 6;
    int wid = (blockIdx.x * 256 + threadIdx.x) >> 6;
    int lane = threadIdx.x & 63;
    int q = lane >> 4, l16 = lane & 15;
    int c = l16 * 8;
    float4 bl = *(const float4*)(b + c);
    float4 bh = *(const float4*)(b + c + 4);
    float bb[8] = {bl.x, bl.y, bl.z, bl.w, bh.x, bh.y, bh.z, bh.w};
    float ls[8] = {0,0,0,0,0,0,0,0};
    float lq[8] = {0,0,0,0,0,0,0,0};
    for (int d = wid; d < N; d += nw) {
        float a0=0.f,a1=0.f,a2=0.f,a3=0.f,a4=0.f,a5=0.f,a6=0.f,a7=0.f;
        int e0 = roff[d], e1 = roff[d + 1];
        for (int e = e0 + q; e < e1; e += 4) {
            int s = srcs[e];
            uint4 u = ((const uint4*)(p + (size_t)s * 128))[l16];
            ACC8(u);
        }
        if (q == 0) { // self term counted once
            uint4 u = ((const uint4*)(p + (size_t)d * 128))[l16];
            ACC8(u);
        }
        a0 += __shfl_xor(a0,16); a0 += __shfl_xor(a0,32);
        a1 += __shfl_xor(a1,16); a1 += __shfl_xor(a1,32);
        a2 += __shfl_xor(a2,16); a2 += __shfl_xor(a2,32);
        a3 += __shfl_xor(a3,16); a3 += __shfl_xor(a3,32);
        a4 += __shfl_xor(a4,16); a4 += __shfl_xor(a4,32);
        a5 += __shfl_xor(a5,16); a5 += __shfl_xor(a5,32);
        a6 += __shfl_xor(a6,16); a6 += __shfl_xor(a6,32);
        a7 += __shfl_xor(a7,16); a7 += __shfl_xor(a7,32);
        if (q == 0) {
            float dv = dinv[d];
            float r0 = dv*a0 + bb[0], r1 = dv*a1 + bb[1];
            float r2 = dv*a2 + bb[2], r3 = dv*a3 + bb[3];
            float r4 = dv*a4 + bb[4], r5 = dv*a5 + bb[5];
            float r6 = dv*a6 + bb[6], r7 = dv*a7 + bb[7];
            ls[0]+=r0; lq[0]+=r0*r0; ls[1]+=r1; lq[1]+=r1*r1;
            ls[2]+=r2; lq[2]+=r2*r2; ls[3]+=r3; lq[3]+=r3*r3;
            ls[4]+=r4; lq[4]+=r4*r4; ls[5]+=r5; lq[5]+=r5*r5;
            ls[6]+=r6; lq[6]+=r6*r6; ls[7]+=r7; lq[7]+=r7*r7;
            uint4 o;
            o.x = packbf(r0, r1); o.y = packbf(r2, r3);
            o.z = packbf(r4, r5); o.w = packbf(r6, r7);
            ((uint4*)(out + (size_t)d * 128))[l16] = o;
        }
    }
    __shared__ float sred[4][128];
    __shared__ float qred[4][128];
    int wv = threadIdx.x >> 6;
    if (q == 0) {
#pragma unroll
        for (int k = 0; k < 8; k++) { sred[wv][c + k] = ls[k]; qred[wv][c + k] = lq[k]; }
    }
    __syncthreads();
    int t = threadIdx.x;
    if (t < 128) {
        float s = sred[0][t] + sred[1][t] + sred[2][t] + sred[3][t];
        float qq = qred[0][t] + qred[1][t] + qred[2][t] + qred[3][t];
        atomicAdd(&gsum[t], s);
        atomicAdd(&gsq[t], qq);
    }
}

// ---------------- GEN precompute: per node row [w(128 bf16) | wm(128 bf16)] ----------------
__global__ __launch_bounds__(256) void k_genpre(const unsigned short* __restrict__ t4,
        const float* __restrict__ scale, const float* __restrict__ shift,
        unsigned short* __restrict__ wt, int N) {
    int i = blockIdx.x * 256 + threadIdx.x;
    int node = i >> 4, l16 = i & 15;
    if (node >= N) return;
    int c = l16 * 8;
    float4 scl = *(const float4*)(scale + c);
    float4 sch = *(const float4*)(scale + c + 4);
    float4 shl = *(const float4*)(shift + c);
    float4 shh = *(const float4*)(shift + c + 4);
    float sc[8] = {scl.x, scl.y, scl.z, scl.w, sch.x, sch.y, sch.z, sch.w};
    float sh[8] = {shl.x, shl.y, shl.z, shl.w, shh.x, shh.y, shh.z, shh.w};
    uint4 u = ((const uint4*)(t4 + (size_t)node * 128))[l16];
    float v[8] = {bflo(u.x), bfhi(u.x), bflo(u.y), bfhi(u.y),
                  bflo(u.z), bfhi(u.z), bflo(u.w), bfhi(u.w)};
    float w[8], wm[8];
#pragma unroll
    for (int k = 0; k < 8; k++) {
        float m = fmaxf(v[k] * sc[k] + sh[k], 0.f) + GEN_EPS;
        m = fminf(m, 80.f);
        w[k] = __expf(m);
        wm[k] = w[k] * m;
    }
    uint4* row = (uint4*)(wt + (size_t)node * 256);
    uint4 ow, om;
    ow.x = packbf(w[0], w[1]); ow.y = packbf(w[2], w[3]);
    ow.z = packbf(w[4], w[5]); ow.w = packbf(w[6], w[7]);
    om.x = packbf(wm[0], wm[1]); om.y = packbf(wm[2], wm[3]);
    om.z = packbf(wm[4], wm[5]); om.w = packbf(wm[6], wm[7]);
    row[l16] = ow;
    row[16 + l16] = om;
}

// ---------------- GEN softmax aggregation: gather precomputed w / wm, sum, divide ----------------
__global__ __launch_bounds__(256) void k_gen_agg(const unsigned short* __restrict__ t4,
        const unsigned short* __restrict__ wt,
        const int* __restrict__ roff, const int* __restrict__ srcs,
        const float* __restrict__ scale, const float* __restrict__ shift,
        unsigned short* __restrict__ out, int N) {
    int nw = (gridDim.x * 256) >> 6;
    int wid = (blockIdx.x * 256 + threadIdx.x) >> 6;
    int lane = threadIdx.x & 63;
    int q = lane >> 4, l16 = lane & 15;
    int c = l16 * 8;
    for (int d = wid; d < N; d += nw) {
        float de[8] = {0,0,0,0,0,0,0,0};
        float nu[8] = {0,0,0,0,0,0,0,0};
        int e0 = roff[d], e1 = roff[d + 1];
        for (int e = e0 + q; e < e1; e += 4) {
            int s = srcs[e];
            const uint4* row = (const uint4*)(wt + (size_t)s * 256);
            uint4 uw = row[l16];
            uint4 um = row[16 + l16];
            de[0] += bflo(uw.x); de[1] += bfhi(uw.x);
            de[2] += bflo(uw.y); de[3] += bfhi(uw.y);
            de[4] += bflo(uw.z); de[5] += bfhi(uw.z);
            de[6] += bflo(uw.w); de[7] += bfhi(uw.w);
            nu[0] += bflo(um.x); nu[1] += bfhi(um.x);
            nu[2] += bflo(um.y); nu[3] += bfhi(um.y);
            nu[4] += bflo(um.z); nu[5] += bfhi(um.z);
            nu[6] += bflo(um.w); nu[7] += bfhi(um.w);
        }
#pragma unroll
        for (int k = 0; k < 8; k++) {
            de[k] += __shfl_xor(de[k],16); de[k] += __shfl_xor(de[k],32);
            nu[k] += __shfl_xor(nu[k],16); nu[k] += __shfl_xor(nu[k],32);
        }
        if (q == 0) {
            float4 scl = *(const float4*)(scale + c);
            float4 sch = *(const float4*)(scale + c + 4);
            float4 shl = *(const float4*)(shift + c);
            float4 shh = *(const float4*)(shift + c + 4);
            float sc[8] = {scl.x, scl.y, scl.z, scl.w, sch.x, sch.y, sch.z, sch.w};
            float sh[8] = {shl.x, shl.y, shl.z, shl.w, shh.x, shh.y, shh.z, shh.w};
            uint4 u = ((const uint4*)(t4 + (size_t)d * 128))[l16];
            float v[8] = {bflo(u.x), bfhi(u.x), bflo(u.y), bfhi(u.y),
                          bflo(u.z), bfhi(u.z), bflo(u.w), bfhi(u.w)};
            float r[8];
            bool has = (e1 > e0);
#pragma unroll
            for (int k = 0; k < 8; k++) {
                float h2 = fmaxf(v[k] * sc[k] + sh[k], 0.f);
                float a = has ? nu[k] / de[k] : 0.f;
                r[k] = a + h2;
            }
            uint4 o;
            o.x = packbf(r[0], r[1]); o.y = packbf(r[2], r[3]);
            o.z = packbf(r[4], r[5]); o.w = packbf(r[6], r[7]);
            ((uint4*)(out + (size_t)d * 128))[l16] = o;
        }
    }
}

__global__ void k_fin(const float* __restrict__ sum, const float* __restrict__ sq,
        const float* __restrict__ g, const float* __restrict__ beta,
        float* __restrict__ scale, float* __restrict__ shift, int D, float invN) {
    int c = threadIdx.x;
    if (c < D) {
        float mu = sum[c] * invN;
        float var = sq[c] * invN - mu * mu;
        float s = g[c] * rsqrtf(var + BN_EPS);
        scale[c] = s;
        shift[c] = beta[c] - mu * s;
    }
}

extern "C" void kernel_launch(void* const* d_in, const int* in_sizes, int n_in,
                              void* d_out, int out_size, void* d_ws, size_t ws_size,
                              hipStream_t stream) {
    const float* x   = (const float*)d_in[0];
    const float* W0  = (const float*)d_in[1];
    const float* b0  = (const float*)d_in[2];
    const float* g0  = (const float*)d_in[3];
    const float* be0 = (const float*)d_in[4];
    const float* W1  = (const float*)d_in[5];
    const float* b1  = (const float*)d_in[6];
    const float* g1  = (const float*)d_in[7];
    const float* be1 = (const float*)d_in[8];
    const float* Wg1 = (const float*)d_in[9];
    const float* bg1 = (const float*)d_in[10];
    const float* gg  = (const float*)d_in[11];
    const float* beg = (const float*)d_in[12];
    const float* Wg2 = (const float*)d_in[13];
    const float* bg2 = (const float*)d_in[14];
    const int*   ei  = (const int*)d_in[15];

    const int N = in_sizes[0] / DIN;
    const int E = in_sizes[15] / 2;
    const int* src = ei;
    const int* dst = ei + E;

    char* ws = (char*)d_ws;
    size_t off = 0;
    auto alloc = [&](size_t b) { size_t o = off; off = (off + b + 255) & ~(size_t)255; return o; };
    size_t o_counts = alloc((size_t)N * 4);
    size_t o_stats  = alloc(1024 * 4);
    size_t o_cursor = alloc((size_t)N * 4);
    size_t o_roff   = alloc(((size_t)N + 1) * 4);
    size_t o_srcs   = alloc((size_t)E * 4);
    size_t o_dinv   = alloc((size_t)N * 4);
    size_t o_bsum   = alloc(1024 * 4);
    size_t o_ss     = alloc(1024 * 4);
    size_t o_w0t    = alloc(128 * 128 * 2);
    size_t o_w1t    = alloc(128 * 128 * 2);
    size_t o_wg1t   = alloc(256 * 128 * 2);
    size_t o_wg2t   = alloc(64 * 256 * 2);
    size_t o_xa     = alloc((size_t)N * 128 * 2);
    size_t o_xb     = alloc((size_t)N * 128 * 2);
    size_t o_c      = alloc((size_t)N * 256 * 2);   // MLP hidden; aliased as GEN exp table
    (void)ws_size; (void)n_in; (void)out_size;

    int* counts = (int*)(ws + o_counts);
    float* stats = (float*)(ws + o_stats);
    int* cursor = (int*)(ws + o_cursor);
    int* roff = (int*)(ws + o_roff);
    int* srcs = (int*)(ws + o_srcs);
    float* dinv = (float*)(ws + o_dinv);
    int* bsum = (int*)(ws + o_bsum);
    float* ssz = (float*)(ws + o_ss);
    unsigned short* w0t  = (unsigned short*)(ws + o_w0t);
    unsigned short* w1t  = (unsigned short*)(ws + o_w1t);
    unsigned short* wg1t = (unsigned short*)(ws + o_wg1t);
    unsigned short* wg2t = (unsigned short*)(ws + o_wg2t);
    unsigned short* xa = (unsigned short*)(ws + o_xa);
    unsigned short* xb = (unsigned short*)(ws + o_xb);
    unsigned short* cb = (unsigned short*)(ws + o_c);
    unsigned short* wtab = cb;  // alias: exp table lives in cb until MLP GEMM overwrites it

    float* sum0 = stats;       float* sq0 = stats + 128;
    float* sum1 = stats + 256; float* sq1 = stats + 384;
    float* sumg = stats + 512; float* sqg = stats + 768;
    float* scale0 = ssz;       float* shift0 = ssz + 128;
    float* scale1 = ssz + 256; float* shift1 = ssz + 384;
    float* scaleg = ssz + 512; float* shiftg = ssz + 768;

    hipMemsetAsync(ws + o_counts, 0, o_cursor - o_counts, stream);

    // CSR build (hierarchical scan)
    int egrid = (E + 255) / 256;
    int nblk = (N + 1023) / 1024;
    k_hist<<<egrid, 256, 0, stream>>>(dst, counts, E);
    k_scan1<<<nblk, 256, 0, stream>>>(counts, roff, bsum, N);
    k_scan2<<<1, 1024, 0, stream>>>(bsum, nblk);
    k_scan3<<<(N + 255) / 256, 256, 0, stream>>>(counts, bsum, roff, cursor, dinv, N, E);
    k_fill<<<egrid, 256, 0, stream>>>(src, dst, cursor, srcs, E);

    // weight transposes (bf16)
    k_wt<<<(128 * 128 + 255) / 256, 256, 0, stream>>>(W0, w0t, 128, 128);
    k_wt<<<(128 * 128 + 255) / 256, 256, 0, stream>>>(W1, w1t, 128, 128);
    k_wt<<<(128 * 256 + 255) / 256, 256, 0, stream>>>(Wg1, wg1t, 128, 256);
    k_wt<<<(256 * 64 + 255) / 256, 256, 0, stream>>>(Wg2, wg2t, 256, 64);

    int rb = (N + 63) / 64;
    const float invN = 1.f / (float)N;

    // layer 0: p0 = dinv.*(x@W0) -> xa ; agg (+fused stats) -> xb ; finalize BN
    k_gemm<128, 128, false, true, false, false><<<dim3(rb, 1), 256, 0, stream>>>(
        x, w0t, nullptr, nullptr, nullptr, dinv, xa, nullptr, nullptr, N, 128);
    k_gcn_agg<<<2048, 256, 0, stream>>>(xa, roff, srcs, dinv, b0, xb, sum0, sq0, N);
    k_fin<<<1, 256, 0, stream>>>(sum0, sq0, g0, be0, scale0, shift0, 128, invN);

    // layer 1
    k_gemm<128, 128, true, true, false, false><<<dim3(rb, 1), 256, 0, stream>>>(
        xb, w1t, nullptr, scale0, shift0, dinv, xa, nullptr, nullptr, N, 128);
    k_gcn_agg<<<2048, 256, 0, stream>>>(xa, roff, srcs, dinv, b1, xb, sum1, sq1, N);
    k_fin<<<1, 256, 0, stream>>>(sum1, sq1, g1, be1, scale1, shift1, 128, invN);

    // GEN conv: precompute exp tables, then gather-sum
    k_genpre<<<(N * 16 + 255) / 256, 256, 0, stream>>>(xb, scale1, shift1, wtab, N);
    k_gen_agg<<<2048, 256, 0, stream>>>(xb, wtab, roff, srcs, scale1, shift1, xa, N);

    // MLP: t7 = t6@Wg1+bg1 -> cb (overwrites exp table), stats fused; finalize BN
    k_gemm<128, 128, true, true, true, false><<<dim3(rb, 2), 256, 0, stream>>>(
        xa, wg1t, bg1, nullptr, nullptr, nullptr, cb, sumg, sqg, N, 256);
    k_fin<<<1, 256, 0, stream>>>(sumg, sqg, gg, beg, scaleg, shiftg, 256, invN);

    // final GEMM + fused log_softmax -> d_out
    k_gemm<256, 64, true, false, false, true><<<dim3(rb, 1), 256, 0, stream>>>(
        cb, wg2t, bg2, scaleg, shiftg, nullptr, d_out, nullptr, nullptr, N, 64);
}